// Round 2
// baseline (274.782 us; speedup 1.0000x reference)
//
#include <hip/hip_runtime.h>

// cost[b,dd,ii,j,c,uv] = (bounds? x[b,c,uv, ii+d*(4-u), j+d*(4-v)] : 0) * mask[b,uv,ii,j]
// d = dd-4, u=uv/9, v=uv%9.  out = cost (b,9,96,96,324) flat, then ctr = x[:,:,40,:,:].
//
// v2: wave-autonomous pipeline. Block=(ii,dd,b), 256 threads = 4 waves; each
// wave owns a private 8-j LDS slice and streams 3 chunks with NO block barriers
// after the LUT (within-wave LDS exchange only needs lgkmcnt + wave_barrier).
// x-loads for chunk k+1 are issued before the store phase of chunk k so the
// NT-store stream hides read latency (issue-early / write-late).

#define NAA 81
#define H 96
#define W 96
#define NC 4
#define ND 9
#define PLANE 9216          // 96*96
#define NR 324              // rows = c*81+uv
#define JBW 8               // j-width per wave chunk
#define SLICE (JBW * NR)    // 2592 floats per wave-private slice
#define OUTROW 31104        // W*NR
#define CTR_OFF 53747712LL  // 2*9*96*96*324
#define XTOT 5971968        // total floats in x

typedef float f32x4 __attribute__((ext_vector_type(4)));
typedef f32x4 __attribute__((aligned(4))) f32x4u;   // 4B-aligned vector load

// Within-wave producer->consumer edge for the wave-private LDS slice:
// drain DS ops + forbid compiler reordering of memory ops across this point.
#define WAVE_SYNC() do { \
    asm volatile("s_waitcnt lgkmcnt(0)" ::: "memory"); \
    __builtin_amdgcn_wave_barrier(); \
} while (0)

__device__ __forceinline__ f32x4 combine(f32x4 xv, f32x4 mv, int xb, int col0) {
    f32x4 r;
    bool rv = xb >= 0;
    r.x = (rv && (unsigned)(col0 + 0) < (unsigned)W) ? xv.x * mv.x : 0.0f;
    r.y = (rv && (unsigned)(col0 + 1) < (unsigned)W) ? xv.y * mv.y : 0.0f;
    r.z = (rv && (unsigned)(col0 + 2) < (unsigned)W) ? xv.z * mv.z : 0.0f;
    r.w = (rv && (unsigned)(col0 + 3) < (unsigned)W) ? xv.w * mv.w : 0.0f;
    return r;
}

__global__ __launch_bounds__(256, 3)
void build_cost_kernel(const float* __restrict__ x, const float* __restrict__ mask,
                       float* __restrict__ out) {
    __shared__ __align__(16) float xs[4 * SLICE];   // 41,472 B (4 wave slices)
    __shared__ __align__(16) int   lut[2 * NR];     //  2,592 B

    const int ii  = blockIdx.x;
    const int dd  = blockIdx.y;
    const int b   = blockIdx.z;
    const int d   = dd - 4;
    const int tid = threadIdx.x;
    const int w    = tid >> 6;
    const int lane = tid & 63;

    // ---- phase 0: packed per-row LUT (324 rows) ----
    for (int row = tid; row < NR; row += 256) {
        int c  = row / 81;
        int uv = row - 81 * c;
        int u  = uv / 9;
        int v  = uv - 9 * u;
        int ri = ii + d * (4 - u);
        int xb = ((b * NC + c) * NAA + uv) * PLANE + ri * W;
        int mb = ((b * NAA + uv) * H + ii) * W;
        int s  = d * (4 - v);
        lut[2 * row]     = ((unsigned)ri < (unsigned)H) ? xb : -1;
        lut[2 * row + 1] = (mb << 6) | (s + 16);
    }
    __syncthreads();   // the ONLY block-wide barrier

    // ---- ctr output: x[b,c,40,ii,:] (one block per (ii,b) at dd==4) ----
    if (dd == 4 && tid < 96) {
        int c = tid / 24;
        int q = tid - 24 * c;
        size_t so  = (size_t)((b * NC + c) * NAA + 40) * PLANE + (size_t)ii * W + 4 * q;
        size_t dst = CTR_OFF + (size_t)((b * NC + c) * H + ii) * W + 4 * q;
        f32x4 cv = *(const f32x4*)(x + so);
        __builtin_nontemporal_store(cv, (f32x4*)(out + dst));
    }

    float* const slice = &xs[w * SLICE];
    const size_t obase = (size_t)((b * ND + dd) * H + ii) * OUTROW;

    // item m: it = lane + 64*m over 162 items = (row-quad rq, j-half jh)
    const int rq0 = lane >> 1;          // m=0
    const int jh  = lane & 1;           // same for all m (64 even)
    const int rq1 = rq0 + 32;           // m=1
    const int rq2 = rq0 + 64;           // m=2, valid for lane < 34
    const bool has2 = (lane < 34);

    f32x4 xr0[4], xr1[4];

    // issue the two full items' x-loads for chunk at j0w (prefetch path)
    auto issue = [&](int j0w) {
        int jb = j0w + 4 * jh;
        {
            int4 P0 = *(const int4*)&lut[8 * rq0];
            int4 P1 = *(const int4*)&lut[8 * rq0 + 4];
            xr0[0] = *(const f32x4u*)(x + min(max(P0.x + jb + ((P0.y & 63) - 16), 0), XTOT - 4));
            xr0[1] = *(const f32x4u*)(x + min(max(P0.z + jb + ((P0.w & 63) - 16), 0), XTOT - 4));
            xr0[2] = *(const f32x4u*)(x + min(max(P1.x + jb + ((P1.y & 63) - 16), 0), XTOT - 4));
            xr0[3] = *(const f32x4u*)(x + min(max(P1.z + jb + ((P1.w & 63) - 16), 0), XTOT - 4));
        }
        {
            int4 P0 = *(const int4*)&lut[8 * rq1];
            int4 P1 = *(const int4*)&lut[8 * rq1 + 4];
            xr1[0] = *(const f32x4u*)(x + min(max(P0.x + jb + ((P0.y & 63) - 16), 0), XTOT - 4));
            xr1[1] = *(const f32x4u*)(x + min(max(P0.z + jb + ((P0.w & 63) - 16), 0), XTOT - 4));
            xr1[2] = *(const f32x4u*)(x + min(max(P1.x + jb + ((P1.y & 63) - 16), 0), XTOT - 4));
            xr1[3] = *(const f32x4u*)(x + min(max(P1.z + jb + ((P1.w & 63) - 16), 0), XTOT - 4));
        }
    };

    // mask-multiply + 4x4 transpose + b128 LDS writes for one item
    auto cw = [&](int rq, int jb, const f32x4* xv) {
        int4 P0 = *(const int4*)&lut[8 * rq];
        int4 P1 = *(const int4*)&lut[8 * rq + 4];
        f32x4 m0 = *(const f32x4*)(mask + (P0.y >> 6) + jb);
        f32x4 m1 = *(const f32x4*)(mask + (P0.w >> 6) + jb);
        f32x4 m2 = *(const f32x4*)(mask + (P1.y >> 6) + jb);
        f32x4 m3 = *(const f32x4*)(mask + (P1.w >> 6) + jb);
        f32x4 v0 = combine(xv[0], m0, P0.x, jb + ((P0.y & 63) - 16));
        f32x4 v1 = combine(xv[1], m1, P0.z, jb + ((P0.w & 63) - 16));
        f32x4 v2 = combine(xv[2], m2, P1.x, jb + ((P1.y & 63) - 16));
        f32x4 v3 = combine(xv[3], m3, P1.z, jb + ((P1.w & 63) - 16));
        float* bp = slice + 4 * rq + (4 * jh) * NR;
        f32x4 t0 = {v0.x, v1.x, v2.x, v3.x};
        f32x4 t1 = {v0.y, v1.y, v2.y, v3.y};
        f32x4 t2 = {v0.z, v1.z, v2.z, v3.z};
        f32x4 t3 = {v0.w, v1.w, v2.w, v3.w};
        *(f32x4*)(bp + 0 * NR) = t0;
        *(f32x4*)(bp + 1 * NR) = t1;
        *(f32x4*)(bp + 2 * NR) = t2;
        *(f32x4*)(bp + 3 * NR) = t3;
    };

    issue(8 * w);   // prologue: chunk 0 x-loads in flight

    #pragma unroll
    for (int k = 0; k < 3; ++k) {
        const int j0w = 8 * (w + 4 * k);
        const int jb  = j0w + 4 * jh;

        // --- third (ragged) item: issue its x-loads first so cw0/cw1 hide them
        f32x4 a0, a1, a2, a3;
        int4 Q0, Q1;
        if (has2) {
            Q0 = *(const int4*)&lut[8 * rq2];
            Q1 = *(const int4*)&lut[8 * rq2 + 4];
            a0 = *(const f32x4u*)(x + min(max(Q0.x + jb + ((Q0.y & 63) - 16), 0), XTOT - 4));
            a1 = *(const f32x4u*)(x + min(max(Q0.z + jb + ((Q0.w & 63) - 16), 0), XTOT - 4));
            a2 = *(const f32x4u*)(x + min(max(Q1.x + jb + ((Q1.y & 63) - 16), 0), XTOT - 4));
            a3 = *(const f32x4u*)(x + min(max(Q1.z + jb + ((Q1.w & 63) - 16), 0), XTOT - 4));
        }

        cw(rq0, jb, xr0);
        cw(rq1, jb, xr1);

        if (has2) {
            f32x4 m0 = *(const f32x4*)(mask + (Q0.y >> 6) + jb);
            f32x4 m1 = *(const f32x4*)(mask + (Q0.w >> 6) + jb);
            f32x4 m2 = *(const f32x4*)(mask + (Q1.y >> 6) + jb);
            f32x4 m3 = *(const f32x4*)(mask + (Q1.w >> 6) + jb);
            f32x4 v0 = combine(a0, m0, Q0.x, jb + ((Q0.y & 63) - 16));
            f32x4 v1 = combine(a1, m1, Q0.z, jb + ((Q0.w & 63) - 16));
            f32x4 v2 = combine(a2, m2, Q1.x, jb + ((Q1.y & 63) - 16));
            f32x4 v3 = combine(a3, m3, Q1.z, jb + ((Q1.w & 63) - 16));
            float* bp = slice + 4 * rq2 + (4 * jh) * NR;
            f32x4 t0 = {v0.x, v1.x, v2.x, v3.x};
            f32x4 t1 = {v0.y, v1.y, v2.y, v3.y};
            f32x4 t2 = {v0.z, v1.z, v2.z, v3.z};
            f32x4 t3 = {v0.w, v1.w, v2.w, v3.w};
            *(f32x4*)(bp + 0 * NR) = t0;
            *(f32x4*)(bp + 1 * NR) = t1;
            *(f32x4*)(bp + 2 * NR) = t2;
            *(f32x4*)(bp + 3 * NR) = t3;
        }

        WAVE_SYNC();               // slice now complete for this wave

        if (k < 2) issue(8 * (w + 4 * (k + 1)));   // prefetch next chunk's x

        // --- phase 2: contiguous NT stores; LDS addr = 16*idx bytes (linear)
        const size_t cb = obase + (size_t)j0w * NR;
        #pragma unroll 2
        for (int m2 = 0; m2 < 10; ++m2) {
            int idx = lane + 64 * m2;
            f32x4 v = *(const f32x4*)(slice + 4 * idx);
            __builtin_nontemporal_store(v, (f32x4*)(out + cb + 4 * (size_t)idx));
        }
        if (lane < 8) {
            int idx = lane + 640;
            f32x4 v = *(const f32x4*)(slice + 4 * idx);
            __builtin_nontemporal_store(v, (f32x4*)(out + cb + 4 * (size_t)idx));
        }

        WAVE_SYNC();               // reads drained before next chunk overwrites
    }
}

extern "C" void kernel_launch(void* const* d_in, const int* in_sizes, int n_in,
                              void* d_out, int out_size, void* d_ws, size_t ws_size,
                              hipStream_t stream) {
    const float* x    = (const float*)d_in[0];
    const float* mask = (const float*)d_in[1];
    float* out = (float*)d_out;
    dim3 grid(96, ND, 2);   // (ii, dd, b)
    build_cost_kernel<<<grid, 256, 0, stream>>>(x, mask, out);
}

// Round 3
// 241.556 us; speedup vs baseline: 1.1376x; 1.1376x over previous
//
#include <hip/hip_runtime.h>

// cost[b,dd,ii,j,c,uv] = (bounds? x[b,c,uv, ii+d*(4-u), j+d*(4-v)] : 0) * mask[b,uv,ii,j]
// d = dd-4, u=uv/9, v=uv%9.  out = cost (b,9,96,96,324) flat, then ctr = x[:,:,40,:,:].
//
// v3 = R1 kernel + XCD-band swizzle (only the blockIdx decode changed).
// Dispatch D: XCD = D&7 (HW round-robin assumption), slot s = D>>3.
// Each XCD owns ii-band [12*xcd, 12*xcd+12) and sweeps (b slow, dd slow,
// jc mid, ii fast), so co-resident blocks on an XCD span ~3 consecutive dd
// -> x working set ~5 MB -> x/mask reuse is captured in the XCD's private L2
// instead of crossing the fabric to L3 81 times per row.

#define NAA 81
#define H 96
#define W 96
#define NC 4
#define ND 9
#define PLANE 9216          // 96*96
#define NR 324              // rows = c*81+uv
#define JB 32               // j per block
#define OUTROW 31104        // W*NR
#define CTR_OFF 53747712LL  // 2*9*96*96*324
#define XTOT 5971968        // total floats in x

typedef float f32x4 __attribute__((ext_vector_type(4)));
typedef f32x4 __attribute__((aligned(4))) f32x4u;   // 4B-aligned vector load

__global__ __launch_bounds__(512, 6)
void build_cost_kernel(const float* __restrict__ x, const float* __restrict__ mask,
                       float* __restrict__ out) {
    __shared__ __align__(16) float xs[JB * NR];   // xs[jj*NR + row]  (41,472 B)
    __shared__ __align__(16) int   lut[2 * NR];   // per row: {xb_or_-1, (mb<<6)|(s+16)}

    // ---- XCD-band swizzle decode ----
    const int D   = blockIdx.x;      // 0..5183
    const int xcd = D & 7;           // target XCD (HW round-robin over dispatch id)
    const int s_  = D >> 3;          // 0..647: slot within XCD
    const int b   = s_ / 324;        // phase 0..1 = batch
    const int w_  = s_ - 324 * b;    // 0..323
    const int dd  = w_ / 36;         // slow: disparity 0..8
    const int r_  = w_ - 36 * dd;
    const int jc  = r_ / 12;         // mid: j-chunk 0..2
    const int iio = r_ - 12 * jc;    // fast: ii within band
    const int ii  = 12 * xcd + iio;  // spatial row
    const int j0  = JB * jc;
    const int d   = dd - 4;
    const int tid = threadIdx.x;

    // ---- phase 0: packed per-row LUT (324 rows) ----
    if (tid < NR) {
        int row = tid;                   // row = c*81 + uv
        int c  = row / 81;
        int uv = row - 81 * c;
        int u  = uv / 9;
        int v  = uv - 9 * u;
        int ri = ii + d * (4 - u);
        int xb = ((b * NC + c) * NAA + uv) * PLANE + ri * W;
        int mb = ((b * NAA + uv) * H + ii) * W;
        int s  = d * (4 - v);
        lut[2 * tid]     = ((unsigned)ri < (unsigned)H) ? xb : -1;
        lut[2 * tid + 1] = (mb << 6) | (s + 16);
    }
    __syncthreads();

    // ---- phase 1: stage 4x4 tiles. item = (row-quad rq, j-quad j4) ----
    for (int idx = tid; idx < NAA * 8; idx += 512) {
        int rq = idx >> 3;               // row quad 0..80
        int j4 = idx & 7;                // j quad 0..7
        int jb = 4 * j4;
        int4 P0 = *(const int4*)&lut[8 * rq];       // rows 4rq, 4rq+1
        int4 P1 = *(const int4*)&lut[8 * rq + 4];   // rows 4rq+2, 4rq+3

        auto ld = [&](int xb, int B) -> f32x4 {
            int s    = (B & 63) - 16;
            int col0 = j0 + jb + s;
            int a0   = xb + col0;
            int addr = min(max(a0, 0), XTOT - 4);
            f32x4 xv = *(const f32x4u*)(x + addr);
            f32x4 mv = *(const f32x4*)(mask + (B >> 6) + j0 + jb);
            f32x4 r;
            bool rv = (xb >= 0);
            r.x = (rv && (unsigned)(col0 + 0) < (unsigned)W) ? xv.x * mv.x : 0.0f;
            r.y = (rv && (unsigned)(col0 + 1) < (unsigned)W) ? xv.y * mv.y : 0.0f;
            r.z = (rv && (unsigned)(col0 + 2) < (unsigned)W) ? xv.z * mv.z : 0.0f;
            r.w = (rv && (unsigned)(col0 + 3) < (unsigned)W) ? xv.w * mv.w : 0.0f;
            return r;
        };

        f32x4 v0 = ld(P0.x, P0.y);
        f32x4 v1 = ld(P0.z, P0.w);
        f32x4 v2 = ld(P1.x, P1.y);
        f32x4 v3 = ld(P1.z, P1.w);

        // transpose 4x4 in registers; column t -> rows 4rq..4rq+3 at jj=jb+t
        float* base = &xs[4 * rq];
        f32x4 w0 = {v0.x, v1.x, v2.x, v3.x};
        f32x4 w1 = {v0.y, v1.y, v2.y, v3.y};
        f32x4 w2 = {v0.z, v1.z, v2.z, v3.z};
        f32x4 w3 = {v0.w, v1.w, v2.w, v3.w};
        *(f32x4*)(base + (jb + 0) * NR) = w0;
        *(f32x4*)(base + (jb + 1) * NR) = w1;
        *(f32x4*)(base + (jb + 2) * NR) = w2;
        *(f32x4*)(base + (jb + 3) * NR) = w3;
    }
    __syncthreads();

    // ---- phase 2: contiguous, aligned stores in output order ----
    // out offset = obase + 4*idx; LDS addr = 16*idx bytes (purely linear,
    // conflict-free b128 reads).
    const size_t obase = (size_t)((b * ND + dd) * H + ii) * OUTROW + (size_t)j0 * NR;
    for (int idx = tid; idx < NAA * JB; idx += 512) {
        f32x4 v = *(const f32x4*)&xs[4 * idx];
        __builtin_nontemporal_store(v, (f32x4*)(out + obase + 4 * (size_t)idx));
    }

    // ---- ctr output: x[b,c,40,ii,:] (done by dd==4, jc==0 blocks) ----
    if (dd == 4 && jc == 0 && tid < 96) {
        int c = tid / 24;
        int q = tid - 24 * c;
        size_t so  = (size_t)((b * NC + c) * NAA + 40) * PLANE + (size_t)ii * W + 4 * q;
        size_t dst = CTR_OFF + (size_t)((b * NC + c) * H + ii) * W + 4 * q;
        f32x4 cv = *(const f32x4*)(x + so);
        __builtin_nontemporal_store(cv, (f32x4*)(out + dst));
    }
}

extern "C" void kernel_launch(void* const* d_in, const int* in_sizes, int n_in,
                              void* d_out, int out_size, void* d_ws, size_t ws_size,
                              hipStream_t stream) {
    const float* x    = (const float*)d_in[0];
    const float* mask = (const float*)d_in[1];
    float* out = (float*)d_out;
    dim3 grid(5184, 1, 1);   // flattened; XCD-band swizzle decoded in-kernel
    build_cost_kernel<<<grid, 512, 0, stream>>>(x, mask, out);
}